// Round 2
// baseline (208.824 us; speedup 1.0000x reference)
//
#include <hip/hip_runtime.h>
#include <math.h>

// Problem constants (fixed by setup_inputs): B=8, C=4, H=W=64, K=8192
#define N_POINTS 32768   // B*H*W
#define KCODES   8192
#define HW       4096
#define CHW      16384
#define NWAVES   8                  // waves per block = code slices
#define SLICE    (KCODES / NWAVES)  // 1024 codes per wave

// ws layout (bytes): cbn float[8192] @ 0  (|c|^2, numpy rounding order)
#define WS_CBN 0

// Bit-exact conv z = W x + b, numpy sequential c-order, no FMA contraction.
__device__ __forceinline__ void compute_z(
    const float* __restrict__ ze, const float* __restrict__ w,
    const float* __restrict__ bias, int n, float zo[4], float& zz) {
  int b = n >> 12, hw = n & 4095;
  const float* p = ze + b * CHW + hw;
  float x0 = p[0], x1 = p[HW], x2 = p[2 * HW], x3 = p[3 * HW];
#pragma unroll
  for (int o = 0; o < 4; ++o) {
    float acc = __fmul_rn(x0, w[o * 4 + 0]);
    acc = __fadd_rn(acc, __fmul_rn(x1, w[o * 4 + 1]));
    acc = __fadd_rn(acc, __fmul_rn(x2, w[o * 4 + 2]));
    acc = __fadd_rn(acc, __fmul_rn(x3, w[o * 4 + 3]));
    zo[o] = __fadd_rn(acc, bias[o]);
  }
  float s = __fmul_rn(zo[0], zo[0]);
  s = __fadd_rn(s, __fmul_rn(zo[1], zo[1]));
  s = __fadd_rn(s, __fmul_rn(zo[2], zo[2]));
  s = __fadd_rn(s, __fmul_rn(zo[3], zo[3]));
  zz = s;
}

// ---------------- Kernel P: |c|^2 table + loss-slot zero -------------------
__global__ __launch_bounds__(256) void vq_prep(
    const float* __restrict__ cb, float* __restrict__ cbn,
    float* __restrict__ out) {
  int t = blockIdx.x * 256 + threadIdx.x;   // grid covers 8192 exactly
  float c0 = cb[t * 4 + 0], c1 = cb[t * 4 + 1];
  float c2 = cb[t * 4 + 2], c3 = cb[t * 4 + 3];
  float s = __fmul_rn(c0, c0);
  s = __fadd_rn(s, __fmul_rn(c1, c1));
  s = __fadd_rn(s, __fmul_rn(c2, c2));
  s = __fadd_rn(s, __fmul_rn(c3, c3));
  cbn[t] = s;
  if (t == 0) out[N_POINTS * 4] = 0.f;      // zero the q_loss slot
}

// bit-exact distance step: d2 = (|z|^2 - sum((2z)*c)) + |c|^2.
// (2z)*c rounds the same exact product as z*(2c): doubling stays exact.
#define DOT(cw, cnv, kloc)                                   \
  {                                                          \
    float d = __fmul_rn(z2_0, (cw).x);                       \
    d = __fadd_rn(d, __fmul_rn(z2_1, (cw).y));               \
    d = __fadd_rn(d, __fmul_rn(z2_2, (cw).z));               \
    d = __fadd_rn(d, __fmul_rn(z2_3, (cw).w));               \
    float s = __fadd_rn(__fsub_rn(zz, d), (cnv));            \
    if (s < best) { best = s; lbest = (kloc); }              \
  }

// ---------------- Kernel M: fused conv + argmin + gather + loss ------------
// 512 blocks x 512 threads. Block owns 64 points (lane<->point); wave wv
// scans codes [1024*wv, 1024*wv+1024). Codes enter via VECTOR loads (all 64
// lanes same address -> one broadcast L2 request): vmcnt is IN-ORDER, so the
// compiler can partial-wait and software-pipeline — unlike round-1's s_load
// path, where unordered SMEM forces lgkmcnt(0) and exposes full latency per
// chunk (the 95us regression: VGPR=24/SGPR=80 showed full scalarization).
// NOTE: wv = tid>>6 deliberately NOT readfirstlane'd — keeps the address
// formally divergent so the compiler does NOT scalarize the loads.
__global__ __launch_bounds__(512, 4) void vq_main(
    const float* __restrict__ ze, const float* __restrict__ w,
    const float* __restrict__ bias, const float* __restrict__ cb,
    const float* __restrict__ cbn, float* __restrict__ out) {
  int tid  = threadIdx.x;
  int lane = tid & 63;
  int wv   = tid >> 6;                 // wave id 0..7 (formally divergent!)
  int n    = blockIdx.x * 64 + lane;   // this lane's point

  float z[4], zz;
  compute_z(ze, w, bias, n, z, zz);    // redundant per wave: ~0.3% of work
  float z2_0 = __fmul_rn(2.f, z[0]), z2_1 = __fmul_rn(2.f, z[1]);
  float z2_2 = __fmul_rn(2.f, z[2]), z2_3 = __fmul_rn(2.f, z[3]);

  const float4* cbv = (const float4*)cb;    // raw codebook, float4 per code
  const float4* cn4 = (const float4*)cbn;   // |c|^2, 4 per float4
  int kbase = wv << 10;                     // slice base (VGPR, wave-uniform)
  int nb    = wv << 8;                      // cn4 chunk base

  float best = INFINITY;
  int lbest = 0;                            // slice-LOCAL index (SGPR select)

  // ping-pong chunk sets A/B, 4 codes each; copy-free rotation via 2x unroll
  float4 a0 = cbv[kbase + 0], a1 = cbv[kbase + 1];
  float4 a2 = cbv[kbase + 2], a3 = cbv[kbase + 3];
  float4 an = cn4[nb + 0];
  float4 b0 = cbv[kbase + 4], b1 = cbv[kbase + 5];
  float4 b2 = cbv[kbase + 6], b3 = cbv[kbase + 7];
  float4 bn = cn4[nb + 1];

  for (int kc = 0; kc < SLICE; kc += 8) {
    int kn = (kc + 8)  & (SLICE - 1);       // wraps harmlessly on last iter
    int km = (kc + 12) & (SLICE - 1);
    DOT(a0, an.x, kc + 0); DOT(a1, an.y, kc + 1);
    DOT(a2, an.z, kc + 2); DOT(a3, an.w, kc + 3);
    a0 = cbv[kbase + kn + 0]; a1 = cbv[kbase + kn + 1];
    a2 = cbv[kbase + kn + 2]; a3 = cbv[kbase + kn + 3];
    an = cn4[nb + (kn >> 2)];
    DOT(b0, bn.x, kc + 4); DOT(b1, bn.y, kc + 5);
    DOT(b2, bn.z, kc + 6); DOT(b3, bn.w, kc + 7);
    b0 = cbv[kbase + km + 0]; b1 = cbv[kbase + km + 1];
    b2 = cbv[kbase + km + 2]; b3 = cbv[kbase + km + 3];
    bn = cn4[nb + (km >> 2)];
  }

  // pack (sortable float, global k): u64 min == (min d2, then min k)
  int gk = kbase + lbest;                   // one v_add, once per wave
  unsigned int u  = __float_as_uint(best);
  unsigned int so = (u & 0x80000000u) ? ~u : (u | 0x80000000u);
  unsigned long long key =
      ((unsigned long long)so << 32) | (unsigned int)gk;

  __shared__ unsigned long long red[NWAVES][64];
  red[wv][lane] = key;
  __syncthreads();

  if (tid < 64) {   // wave 0 finishes its 64 points (z still live in regs)
    unsigned long long m = red[0][lane];
#pragma unroll
    for (int i = 1; i < NWAVES; ++i) {
      unsigned long long v = red[i][lane];
      if (v < m) m = v;
    }
    int idx = (int)(unsigned int)(m & 0xFFFFFFFFull);
    float4 c = ((const float4*)cb)[idx];  // bit-exact gather (16B aligned)
    int b = n >> 12, hw = n & 4095;
    float* o = out + b * CHW + hw;
    o[0] = c.x; o[HW] = c.y; o[2 * HW] = c.z; o[3 * HW] = c.w;
    float d0 = c.x - z[0], d1 = c.y - z[1];
    float d2 = c.z - z[2], d3 = c.w - z[3];
    float e = d0 * d0 + d1 * d1 + d2 * d2 + d3 * d3;
#pragma unroll
    for (int off = 32; off > 0; off >>= 1) e += __shfl_down(e, off, 64);
    // q_loss = (1 + BETA) * mean over 131072 elements
    if (lane == 0) atomicAdd(out + (N_POINTS * 4), e * (1.25f / 131072.f));
  }
}

extern "C" void kernel_launch(void* const* d_in, const int* in_sizes, int n_in,
                              void* d_out, int out_size, void* d_ws, size_t ws_size,
                              hipStream_t stream) {
  const float* ze   = (const float*)d_in[0];  // z_e_in [8,4,64,64]
  const float* w    = (const float*)d_in[1];  // pq_w [4,4]
  const float* bias = (const float*)d_in[2];  // pq_b [4]
  const float* cb   = (const float*)d_in[3];  // codebook [8192,4]

  float* cbn = (float*)((char*)d_ws + WS_CBN);
  float* out = (float*)d_out;

  vq_prep<<<32, 256, 0, stream>>>(cb, cbn, out);
  vq_main<<<N_POINTS / 64, 512, 0, stream>>>(ze, w, bias, cb, cbn, out);
}

// Round 3
// 127.437 us; speedup vs baseline: 1.6386x; 1.6386x over previous
//
#include <hip/hip_runtime.h>
#include <math.h>

// Problem constants (fixed by setup_inputs): B=8, C=4, H=W=64, K=8192
#define N_POINTS 32768   // B*H*W
#define KCODES   8192
#define HW       4096
#define CHW      16384

#define NWAVES  16                  // waves per block = code slices
#define SLICE   (KCODES / NWAVES)   // 512 codes per wave
#define CHUNK   64                  // codes staged per LDS chunk (1 per lane)
#define NCHUNK  (SLICE / CHUNK)     // 8
#define PPT     2                   // points per lane
#define PBLK    (64 * PPT)          // 128 points per block
#define NBLK    (N_POINTS / PBLK)   // 256 blocks = 1/CU, 4 waves/SIMD

typedef float f2 __attribute__((ext_vector_type(2)));
typedef float f4 __attribute__((ext_vector_type(4)));

// Packed fp32: 2 IEEE-RN ops per issue slot. Bitwise == scalar v_mul/v_add
// per half — this halves the 9-slot dot/bias chain without touching rounding.
static __device__ __forceinline__ f2 pk_mul(f2 a, f2 b) {
  f2 d;
  asm("v_pk_mul_f32 %0, %1, %2" : "=v"(d) : "v"(a), "v"(b));
  return d;
}
static __device__ __forceinline__ f2 pk_add(f2 a, f2 b) {
  f2 d;
  asm("v_pk_add_f32 %0, %1, %2" : "=v"(d) : "v"(a), "v"(b));
  return d;
}

// Bit-exact conv z = W x + b, numpy sequential c-order, no FMA contraction.
__device__ __forceinline__ void compute_z(
    const float* __restrict__ ze, const float* __restrict__ w,
    const float* __restrict__ bias, int n, float zo[4], float& zz) {
  int b = n >> 12, hw = n & 4095;
  const float* p = ze + b * CHW + hw;
  float x0 = p[0], x1 = p[HW], x2 = p[2 * HW], x3 = p[3 * HW];
#pragma unroll
  for (int o = 0; o < 4; ++o) {
    float acc = __fmul_rn(x0, w[o * 4 + 0]);
    acc = __fadd_rn(acc, __fmul_rn(x1, w[o * 4 + 1]));
    acc = __fadd_rn(acc, __fmul_rn(x2, w[o * 4 + 2]));
    acc = __fadd_rn(acc, __fmul_rn(x3, w[o * 4 + 3]));
    zo[o] = __fadd_rn(acc, bias[o]);
  }
  float s = __fmul_rn(zo[0], zo[0]);
  s = __fadd_rn(s, __fmul_rn(zo[1], zo[1]));
  s = __fadd_rn(s, __fmul_rn(zo[2], zo[2]));
  s = __fadd_rn(s, __fmul_rn(zo[3], zo[3]));
  zz = s;
}

// ---------------- single fused kernel ---------------------------------------
// 256 blocks x 1024 threads (16 waves). Block owns 128 points (PPT=2/lane);
// wave wv scans codes [512*wv, 512*wv+512), staged SoA (-2c0..-2c3, |c|^2)
// into a wave-private LDS double buffer — no in-loop barriers, waves drift.
// Rounding chain (bitwise == ref):
//   round(z_i * (-2c_i)) = -2*round(z_i*c_i)   (pow2 scale + sign are exact)
//   dn = (((z0m0+z1m1)+z2m2)+z3m3) = -2*round(dot)
//   s  = (zz + dn) + cn  ==  (|z|^2 - 2*dot) + |c|^2  left-to-right
__global__ __launch_bounds__(1024, 4) void vq_main(
    const float* __restrict__ ze, const float* __restrict__ w,
    const float* __restrict__ bias, const float* __restrict__ cb,
    float* __restrict__ out) {
  __shared__ float lds[NWAVES][2][5][CHUNK] __attribute__((aligned(16)));
  __shared__ unsigned long long red[NWAVES][PPT][64];

  int tid = threadIdx.x;
  int lane = tid & 63;
  int wv = tid >> 6;
  int nb = blockIdx.x * PBLK;

  f2 zv[PPT][4], zzv[PPT];
#pragma unroll
  for (int p = 0; p < PPT; ++p) {
    float z[4], zz;
    compute_z(ze, w, bias, nb + p * 64 + lane, z, zz);
#pragma unroll
    for (int c = 0; c < 4; ++c) zv[p][c] = (f2){z[c], z[c]};
    zzv[p] = (f2){zz, zz};
  }

  const f4* cbv = (const f4*)cb;
  int kbase = wv * SLICE;
  float best[PPT];
  int bidx[PPT];
#pragma unroll
  for (int p = 0; p < PPT; ++p) { best[p] = INFINITY; bidx[p] = 0; }

  // prologue: stage chunk 0 into buf 0 (lane l -> code kbase + l)
  {
    f4 c = cbv[kbase + lane];
    float m0 = __fmul_rn(-2.f, c.x), m1 = __fmul_rn(-2.f, c.y);
    float m2 = __fmul_rn(-2.f, c.z), m3 = __fmul_rn(-2.f, c.w);
    float cn = __fmul_rn(c.x, c.x);
    cn = __fadd_rn(cn, __fmul_rn(c.y, c.y));
    cn = __fadd_rn(cn, __fmul_rn(c.z, c.z));
    cn = __fadd_rn(cn, __fmul_rn(c.w, c.w));
    float (*Lw)[CHUNK] = lds[wv][0];
    Lw[0][lane] = m0; Lw[1][lane] = m1; Lw[2][lane] = m2;
    Lw[3][lane] = m3; Lw[4][lane] = cn;
  }
  __builtin_amdgcn_wave_barrier();

  for (int t = 0; t < NCHUNK; ++t) {
    // issue next-chunk global load first (hides under this chunk's compute)
    f4 cnx = cbv[kbase + ((t + 1) & (NCHUNK - 1)) * CHUNK + lane];
    const float (*L)[CHUNK] = lds[wv][t & 1];
    int koff = kbase + t * CHUNK;
#pragma unroll 2
    for (int j = 0; j < CHUNK; j += 4) {
      f4 q0 = *(const f4*)&L[0][j];   // -2c0 for codes j..j+3 (broadcast)
      f4 q1 = *(const f4*)&L[1][j];
      f4 q2 = *(const f4*)&L[2][j];
      f4 q3 = *(const f4*)&L[3][j];
      f4 qn = *(const f4*)&L[4][j];   // |c|^2
#pragma unroll
      for (int p = 0; p < PPT; ++p) {
        f2 dA = pk_mul(zv[p][0], q0.xy);
        dA = pk_add(dA, pk_mul(zv[p][1], q1.xy));
        dA = pk_add(dA, pk_mul(zv[p][2], q2.xy));
        dA = pk_add(dA, pk_mul(zv[p][3], q3.xy));
        f2 sA = pk_add(pk_add(zzv[p], dA), qn.xy);
        f2 dB = pk_mul(zv[p][0], q0.zw);
        dB = pk_add(dB, pk_mul(zv[p][1], q1.zw));
        dB = pk_add(dB, pk_mul(zv[p][2], q2.zw));
        dB = pk_add(dB, pk_mul(zv[p][3], q3.zw));
        f2 sB = pk_add(pk_add(zzv[p], dB), qn.zw);
        // ascending k, strict < : first-min (matches jnp.argmin)
        if (sA.x < best[p]) { best[p] = sA.x; bidx[p] = koff + j + 0; }
        if (sA.y < best[p]) { best[p] = sA.y; bidx[p] = koff + j + 1; }
        if (sB.x < best[p]) { best[p] = sB.x; bidx[p] = koff + j + 2; }
        if (sB.y < best[p]) { best[p] = sB.y; bidx[p] = koff + j + 3; }
      }
    }
    // stage chunk t+1 into the other buffer (wraps harmlessly on last iter)
    float m0 = __fmul_rn(-2.f, cnx.x), m1 = __fmul_rn(-2.f, cnx.y);
    float m2 = __fmul_rn(-2.f, cnx.z), m3 = __fmul_rn(-2.f, cnx.w);
    float cn = __fmul_rn(cnx.x, cnx.x);
    cn = __fadd_rn(cn, __fmul_rn(cnx.y, cnx.y));
    cn = __fadd_rn(cn, __fmul_rn(cnx.z, cnx.z));
    cn = __fadd_rn(cn, __fmul_rn(cnx.w, cnx.w));
    float (*Lw)[CHUNK] = lds[wv][(t + 1) & 1];
    Lw[0][lane] = m0; Lw[1][lane] = m1; Lw[2][lane] = m2;
    Lw[3][lane] = m3; Lw[4][lane] = cn;
    __builtin_amdgcn_wave_barrier();
  }

  // pack (sortable d2, global k): u64 min == (min d2, then min k)
#pragma unroll
  for (int p = 0; p < PPT; ++p) {
    unsigned int u = __float_as_uint(best[p]);
    unsigned int so = (u & 0x80000000u) ? ~u : (u | 0x80000000u);
    red[wv][p][lane] =
        ((unsigned long long)so << 32) | (unsigned int)bidx[p];
  }
  __syncthreads();

  if (tid < 64) {   // wave 0 finishes the block's 128 points
    float e = 0.f;
#pragma unroll
    for (int p = 0; p < PPT; ++p) {
      unsigned long long m = red[0][p][lane];
#pragma unroll
      for (int i = 1; i < NWAVES; ++i) {
        unsigned long long v = red[i][p][lane];
        if (v < m) m = v;
      }
      int idx = (int)(unsigned int)(m & 0xFFFFFFFFull);
      f4 c = cbv[idx];                 // bit-exact gather (16B aligned)
      int n = nb + p * 64 + lane;
      int b = n >> 12, hw = n & 4095;
      float* o = out + b * CHW + hw;
      o[0] = c.x; o[HW] = c.y; o[2 * HW] = c.z; o[3 * HW] = c.w;
      float z[4], zz;
      compute_z(ze, w, bias, n, z, zz);
      float d0 = c.x - z[0], d1 = c.y - z[1];
      float d2 = c.z - z[2], d3 = c.w - z[3];
      e += d0 * d0 + d1 * d1 + d2 * d2 + d3 * d3;
    }
#pragma unroll
    for (int off = 32; off > 0; off >>= 1) e += __shfl_down(e, off, 64);
    // q_loss = (1 + BETA) * mean over 131072 elements
    if (lane == 0) atomicAdd(out + (N_POINTS * 4), e * (1.25f / 131072.f));
  }
}

extern "C" void kernel_launch(void* const* d_in, const int* in_sizes, int n_in,
                              void* d_out, int out_size, void* d_ws, size_t ws_size,
                              hipStream_t stream) {
  const float* ze   = (const float*)d_in[0];  // z_e_in [8,4,64,64]
  const float* w    = (const float*)d_in[1];  // pq_w [4,4]
  const float* bias = (const float*)d_in[2];  // pq_b [4]
  const float* cb   = (const float*)d_in[3];  // codebook [8192,4]
  float* out = (float*)d_out;

  // zero the q_loss accumulator slot (4 bytes at float index 131072)
  hipMemsetAsync((char*)d_out + (size_t)N_POINTS * 4 * sizeof(float), 0,
                 sizeof(float), stream);
  vq_main<<<NBLK, 1024, 0, stream>>>(ze, w, bias, cb, out);
}